// Round 8
// baseline (558.590 us; speedup 1.0000x reference)
//
#include <hip/hip_runtime.h>
#include <hip/hip_bf16.h>
#include <cstdint>

static constexpr int N_  = 16384;
static constexpr int E_  = 131072;
static constexpr int D_  = 768;
static constexpr int D2_ = 1536;
static constexpr int DSQ_ = D_ * D_;

// ---------------- workspace layout (bytes), total ~219.3 MB ----------------
static constexpr size_t OFF_XB   = 0;            // N*D bf16    = 25165824
static constexpr size_t OFF_WCT  = 25165824;     // 12*D*D bf16 = 14155776
static constexpr size_t OFF_WLT  = 39321600;     // D*2D bf16   = 2359296
static constexpr size_t OFF_NB16 = 41680896;     // N*2D bf16   = 50331648
static constexpr size_t OFF_H4   = 92012544;     // 4 * N*D bf16 = 100663296
static constexpr size_t OFF_ZB   = 92012544;     // N*D fp32 (reuses H4 after gathers)
static constexpr size_t OFF_N1C  = 192675840;    // N*D bf16 carry = 25165824
static constexpr size_t OFF_TG   = 217841664;    // E int32     = 524288
static constexpr size_t OFF_PAY  = 218365952;    // E int32     = 524288
static constexpr size_t OFF_CNT  = 218890240;    // N*4 int32   = 262144
static constexpr size_t OFF_BASE = 219152384;    // (N+1) int32, padded to 65552
static constexpr size_t OFF_CUR  = 219217936;    // N int32     = 65536
static constexpr size_t OFF_BC   = 219283472;    // 512 int32
static constexpr size_t OFF_SCAN = 219285520;    // 513 int32

typedef __attribute__((ext_vector_type(8))) short short8v;
typedef __attribute__((ext_vector_type(4))) float floatx4;

__device__ __forceinline__ void gld16(const void* g, void* l) {
  __builtin_amdgcn_global_load_lds(
      (const __attribute__((address_space(1))) unsigned int*)g,
      (__attribute__((address_space(3))) unsigned int*)l, 16, 0, 0);
}

__device__ __forceinline__ float b2f(short u) {
  union { unsigned int i; float f; } x;
  x.i = ((unsigned int)(unsigned short)u) << 16;
  return x.f;
}

__device__ __forceinline__ float wave_sum(float v) {
#pragma unroll
  for (int o = 32; o; o >>= 1) v += __shfl_down(v, o, 64);
  return v;
}

// WcT[ft][h][d] = sum_b coeff_f[t,b] * W_f[b][d][h]  (bf16, transposed)
__global__ __launch_bounds__(256) void combine_wt_kernel(
    const float* __restrict__ Wt, const float* __restrict__ ct,
    const float* __restrict__ Wu, const float* __restrict__ cu,
    const float* __restrict__ Wd, const float* __restrict__ cd,
    __hip_bfloat16* __restrict__ WcT) {
  int i  = blockIdx.x * 256 + threadIdx.x;   // < D*D, i = d*768 + h
  int ft = blockIdx.y;                        // 0..11
  int f = ft >> 2, t = ft & 3;
  const float* W = (f == 0) ? Wt : ((f == 1) ? Wu : Wd);
  const float* c = ((f == 0) ? ct : ((f == 1) ? cu : cd)) + t * 3;
  float v = c[0] * W[i] + c[1] * W[DSQ_ + i] + c[2] * W[2 * DSQ_ + i];
  int d = i / D_, h = i % D_;
  WcT[(size_t)ft * DSQ_ + (size_t)h * D_ + d] = __float2bfloat16(v);
}

// W_linT[h][k] = W_lin[k][h] (bf16)
__global__ __launch_bounds__(256) void wlint_kernel(
    const float* __restrict__ W, __hip_bfloat16* __restrict__ WT) {
  int i = blockIdx.x * 256 + threadIdx.x;    // < 2D*D, i = k*768 + h
  int k = i / D_, h = i % D_;
  WT[(size_t)h * D2_ + k] = __float2bfloat16(W[i]);
}

__global__ __launch_bounds__(256) void ln_kernel(
    const float* __restrict__ h, const float* __restrict__ gamma,
    const float* __restrict__ beta, __hip_bfloat16* __restrict__ x) {
  int v = blockIdx.x, tid = threadIdx.x;
  const float* hr = h + (size_t)v * D_;
  float e0 = hr[tid], e1 = hr[tid + 256], e2 = hr[tid + 512];
  float s = e0 + e1 + e2;
  float q = e0 * e0 + e1 * e1 + e2 * e2;
  __shared__ float red[8];
  __shared__ float mv[2];
  float ws_ = wave_sum(s), wq = wave_sum(q);
  int lane = tid & 63, w = tid >> 6;
  if (lane == 0) { red[w] = ws_; red[4 + w] = wq; }
  __syncthreads();
  if (tid == 0) {
    float S = red[0] + red[1] + red[2] + red[3];
    float Q = red[4] + red[5] + red[6] + red[7];
    float mu = S * (1.0f / D_);
    float var = Q * (1.0f / D_) - mu * mu;
    mv[0] = mu;
    mv[1] = rsqrtf(var + 1e-5f);
  }
  __syncthreads();
  float mu = mv[0], rstd = mv[1];
  __hip_bfloat16* xr = x + (size_t)v * D_;
  xr[tid]       = __float2bfloat16((e0 - mu) * rstd * gamma[tid]       + beta[tid]);
  xr[tid + 256] = __float2bfloat16((e1 - mu) * rstd * gamma[tid + 256] + beta[tid + 256]);
  xr[tid + 512] = __float2bfloat16((e2 - mu) * rstd * gamma[tid + 512] + beta[tid + 512]);
}

// per-block hete counts + (dst,etype) histogram
__global__ __launch_bounds__(256) void edge_a_kernel(
    const int* __restrict__ hete, const int* __restrict__ dst,
    const int* __restrict__ etype, int* __restrict__ blockcnt,
    int* __restrict__ cnt4) {
  int j = blockIdx.x * 256 + threadIdx.x;
  int flag = hete[j] > 0;
  unsigned long long m = __ballot(flag);
  __shared__ int wsum[4];
  int lane = threadIdx.x & 63, w = threadIdx.x >> 6;
  if (lane == 0) wsum[w] = __popcll(m);
  __syncthreads();
  if (threadIdx.x == 0)
    blockcnt[blockIdx.x] = wsum[0] + wsum[1] + wsum[2] + wsum[3];
  atomicAdd(&cnt4[dst[j] * 4 + etype[j]], 1);
}

// single-block scan over 512 block counts -> exclusive offsets + total K
__global__ __launch_bounds__(512) void scan_kernel(
    const int* __restrict__ blockcnt, int* __restrict__ scanout) {
  __shared__ int s[512];
  int t = threadIdx.x;
  int v = blockcnt[t];
  s[t] = v;
  __syncthreads();
  for (int o = 1; o < 512; o <<= 1) {
    int add = (t >= o) ? s[t - o] : 0;
    __syncthreads();
    s[t] += add;
    __syncthreads();
  }
  scanout[t] = s[t] - v;             // exclusive prefix
  if (t == 511) scanout[512] = s[511];  // total hete count K
}

// target[j] = dst[perm_inv[j]]
__global__ __launch_bounds__(256) void edge_b_kernel(
    const int* __restrict__ hete, const int* __restrict__ dst,
    const int* __restrict__ scanout, int* __restrict__ target) {
  int j = blockIdx.x * 256 + threadIdx.x;
  int flag = hete[j] > 0;
  unsigned long long m = __ballot(flag);
  __shared__ int wsum[4];
  int lane = threadIdx.x & 63, w = threadIdx.x >> 6;
  if (lane == 0) wsum[w] = __popcll(m);
  __syncthreads();
  int wpre = 0;
#pragma unroll
  for (int i = 0; i < 4; i++) wpre += (i < w) ? wsum[i] : 0;
  int lpre = __popcll(m & ((1ull << lane) - 1ull));
  int hcum = scanout[blockIdx.x] + wpre + lpre;  // # hete edges with idx < j
  int K = scanout[512];
  int e = flag ? hcum : (K + j - hcum);
  target[j] = dst[e];
}

// base[v] = exclusive prefix of deg[v] = sum_t cnt4[v,t]; base[N]=E
__global__ __launch_bounds__(1024) void base_scan_kernel(
    const int* __restrict__ cnt4, int* __restrict__ base) {
  __shared__ int s[1024];
  int t = threadIdx.x;
  int loc[16];
  int sum = 0;
#pragma unroll
  for (int i = 0; i < 16; i++) {
    int v = t * 16 + i;
    int d = cnt4[v * 4] + cnt4[v * 4 + 1] + cnt4[v * 4 + 2] + cnt4[v * 4 + 3];
    loc[i] = sum;
    sum += d;
  }
  s[t] = sum;
  __syncthreads();
  for (int o = 1; o < 1024; o <<= 1) {
    int add = (t >= o) ? s[t - o] : 0;
    __syncthreads();
    s[t] += add;
    __syncthreads();
  }
  int pre = t ? s[t - 1] : 0;
#pragma unroll
  for (int i = 0; i < 16; i++) base[t * 16 + i] = pre + loc[i];
  if (t == 1023) base[N_] = s[1023];
}

// payload[base[target[j]] + cursor++] = g<<14 | src[j]
__global__ __launch_bounds__(256) void edge_sort_kernel(
    const int* __restrict__ target, const int* __restrict__ src,
    const int* __restrict__ etype, const int* __restrict__ hete,
    const int* __restrict__ base, int* __restrict__ cursor,
    int* __restrict__ payload) {
  int j = blockIdx.x * 256 + threadIdx.x;
  int v = target[j];
  int p = base[v] + atomicAdd(&cursor[v], 1);
  int g = ((hete[j] > 0) ? 0 : 4) + etype[j];
  payload[p] = (g << 14) | src[j];
}

// one wave per node; groups [g0, g0+4). Lane owns elems [lane*8,+8) and
// [512+lane*4,+4) -> 16B + 8B vector loads per edge row (G13).
template <bool FIRST>
__global__ __launch_bounds__(256) void gather_n1_kernel(
    const __hip_bfloat16* __restrict__ H, const int* __restrict__ base,
    const int* __restrict__ payload, __hip_bfloat16* __restrict__ n1c,
    __hip_bfloat16* __restrict__ nb16, int g0) {
  int wv = threadIdx.x >> 6, lane = threadIdx.x & 63;
  int v = blockIdx.x * 4 + wv;
  int b0 = base[v], b1 = base[v + 1];
  float acc[12];
  if (FIRST) {
#pragma unroll
    for (int i = 0; i < 12; i++) acc[i] = 0.f;
  } else {
    short8v a8 = *(const short8v*)(n1c + (size_t)v * D_ + lane * 8);
    short4  b4 = *(const short4*)(n1c + (size_t)v * D_ + 512 + lane * 4);
#pragma unroll
    for (int i = 0; i < 8; i++) acc[i] = b2f(a8[i]);
    acc[8] = b2f(b4.x); acc[9] = b2f(b4.y);
    acc[10] = b2f(b4.z); acc[11] = b2f(b4.w);
  }
  for (int idx = b0; idx < b1; ++idx) {
    int pl = payload[idx];
    int g = (pl >> 14) - g0;
    if ((unsigned)g > 3u) continue;
    const __hip_bfloat16* row = H + ((size_t)g * N_ + (pl & 16383)) * D_;
    short8v a8 = *(const short8v*)(row + lane * 8);
    short4  b4 = *(const short4*)(row + 512 + lane * 4);
#pragma unroll
    for (int i = 0; i < 8; i++) acc[i] += b2f(a8[i]);
    acc[8] += b2f(b4.x); acc[9] += b2f(b4.y);
    acc[10] += b2f(b4.z); acc[11] += b2f(b4.w);
  }
  __hip_bfloat16 o[12];
#pragma unroll
  for (int i = 0; i < 12; i++) o[i] = __float2bfloat16(acc[i]);
  if (FIRST) {
    *(short8v*)(n1c + (size_t)v * D_ + lane * 8) = *(const short8v*)o;
    *(short4*)(n1c + (size_t)v * D_ + 512 + lane * 4) = *(const short4*)(o + 8);
  } else {
    *(short8v*)(nb16 + (size_t)v * D2_ + lane * 8) = *(const short8v*)o;
    *(short4*)(nb16 + (size_t)v * D2_ + 512 + lane * 4) = *(const short4*)(o + 8);
  }
}

// nb16[v][768+k] = sum_t cnt4[v,t] * H4[t][v][k]; thread per 8 elems
__global__ __launch_bounds__(256) void combine_n2_kernel(
    const __hip_bfloat16* __restrict__ H4, const int* __restrict__ cnt4,
    __hip_bfloat16* __restrict__ nb16) {
  size_t i = ((size_t)blockIdx.x * 256 + threadIdx.x) * 8;  // < N*D
  int v = (int)(i / D_);
  int k = (int)(i % D_);
  float acc[8] = {0.f, 0.f, 0.f, 0.f, 0.f, 0.f, 0.f, 0.f};
#pragma unroll
  for (int t = 0; t < 4; t++) {
    float c = (float)cnt4[v * 4 + t];
    if (c != 0.f) {
      short8v hv = *(const short8v*)(H4 + (size_t)t * N_ * D_ + i);
#pragma unroll
      for (int j = 0; j < 8; j++) acc[j] += c * b2f(hv[j]);
    }
  }
  __hip_bfloat16 o[8];
#pragma unroll
  for (int j = 0; j < 8; j++) o[j] = __float2bfloat16(acc[j]);
  *(short8v*)(nb16 + (size_t)v * D2_ + D_ + k) = *(const short8v*)o;
}

// Stage one 128-row x 64-col bf16 unit (16 KB) into LDS (linear dest,
// inverse-swizzled global source: slot ^= row&7 on 16B slots of 128B rows).
__device__ __forceinline__ void stage_unit(const __hip_bfloat16* src, int K,
                                           int row_base, int k0,
                                           char* ldsbase, int tid) {
#pragma unroll
  for (int j = 0; j < 2; j++) {
    int r = j * 64 + (tid >> 3);
    int sp = (tid & 7) ^ (r & 7);
    gld16(src + (size_t)(row_base + r) * K + k0 + sp * 8,
          ldsbase + j * 8192 + tid * 16);
  }
}

// C[z][M,N] = relu(A[M,K] @ BT[z][N,K]^T (+bias)). 256x128 tile, BK=64,
// 8 waves (4M x 2N, per-wave 64x64), 3-deep K-tile LDS pipeline (3 x 48 KB),
// 2 phases/K-tile: {12 ds_read_b128 | stage K-tile k+2 | barrier | lgkmcnt(0)
// | setprio(1) 16 MFMA setprio(0) | [vmcnt(6) at tile boundary] | barrier}.
// Counted vmcnt(6): the 6 staging instrs of tile k+2 stay in flight across
// the boundary (T3+T4). XOR-swizzled LDS (T2), raw barriers, XCD swizzle (T1).
template <bool BIAS, bool OUTBF16>
__global__ __launch_bounds__(512) void gemm256_kernel(
    const __hip_bfloat16* __restrict__ A, const __hip_bfloat16* __restrict__ BT0,
    const float* __restrict__ bias, void* __restrict__ Cv,
    int M, int N, int K, size_t strideB, size_t strideC) {
  const __hip_bfloat16* BT = BT0 + (size_t)blockIdx.z * strideB;
  __shared__ char lds[147456];               // 3 bufs x (A 32K + B 16K)
  const int tid = threadIdx.x;
  const int lane = tid & 63;
  const int wv = tid >> 6;
  const int wr = wv >> 1, wc = wv & 1;       // 4M x 2N wave grid
  int nwg = gridDim.x * gridDim.y;           // %8 == 0 for all our shapes
  int id = blockIdx.y * gridDim.x + blockIdx.x;
  int sz = (id & 7) * (nwg >> 3) + (id >> 3);
  int bx = sz % gridDim.x, by = sz / gridDim.x;
  int row0 = by * 256, col0 = bx * 128;
  const int nt = K >> 6;

  floatx4 acc[4][4];
#pragma unroll
  for (int i = 0; i < 4; i++)
#pragma unroll
    for (int j = 0; j < 4; j++) acc[i][j] = floatx4{0.f, 0.f, 0.f, 0.f};

  // prologue: stage K-tiles 0 and 1 (6 instrs each per wave)
#pragma unroll
  for (int kk = 0; kk < 2; kk++) {
    char* nb = lds + kk * 49152;
    stage_unit(A, K, row0, kk * 64, nb, tid);
    stage_unit(A, K, row0 + 128, kk * 64, nb + 16384, tid);
    stage_unit(BT, K, col0, kk * 64, nb + 32768, tid);
  }
  asm volatile("s_waitcnt vmcnt(6)" ::: "memory");   // tile 0 landed
  __builtin_amdgcn_s_barrier();
  asm volatile("" ::: "memory");

  for (int k = 0; k < nt; k++) {
    char* buf = lds + (k % 3) * 49152;
#pragma unroll
    for (int ph = 0; ph < 2; ph++) {
      short8v af[4][2], bf[2][2];
#pragma unroll
      for (int m = 0; m < 4; m++) {
        int ra = wr * 64 + m * 16 + (lane & 15);
#pragma unroll
        for (int ks = 0; ks < 2; ks++) {
          int p = ks * 4 + (lane >> 4);
          af[m][ks] = *(const short8v*)(buf + ra * 128 + ((p ^ (ra & 7)) << 4));
        }
      }
#pragma unroll
      for (int n = 0; n < 2; n++) {
        int cb = wc * 64 + ph * 32 + n * 16 + (lane & 15);
#pragma unroll
        for (int ks = 0; ks < 2; ks++) {
          int p = ks * 4 + (lane >> 4);
          bf[n][ks] = *(const short8v*)(buf + 32768 + cb * 128 +
                                        ((p ^ (cb & 7)) << 4));
        }
      }
      if (k + 2 < nt) {
        char* nb = lds + ((k + 2) % 3) * 49152;
        if (ph == 0) {
          stage_unit(A, K, row0, (k + 2) * 64, nb, tid);
          stage_unit(A, K, row0 + 128, (k + 2) * 64, nb + 16384, tid);
        } else {
          stage_unit(BT, K, col0, (k + 2) * 64, nb + 32768, tid);
        }
      }
      __builtin_amdgcn_s_barrier();
      asm volatile("s_waitcnt lgkmcnt(0)" ::: "memory");
      __builtin_amdgcn_s_setprio(1);
#pragma unroll
      for (int m = 0; m < 4; m++)
#pragma unroll
        for (int n = 0; n < 2; n++)
#pragma unroll
          for (int ks = 0; ks < 2; ks++)
            acc[m][ph * 2 + n] = __builtin_amdgcn_mfma_f32_16x16x32_bf16(
                af[m][ks], bf[n][ks], acc[m][ph * 2 + n], 0, 0, 0);
      __builtin_amdgcn_s_setprio(0);
      if (ph == 1 && k + 1 < nt) {
        if (k + 2 < nt) asm volatile("s_waitcnt vmcnt(6)" ::: "memory");
        else            asm volatile("s_waitcnt vmcnt(0)" ::: "memory");
      }
      __builtin_amdgcn_s_barrier();
      asm volatile("" ::: "memory");
    }
  }
  // epilogue: C/D layout col=lane&15, row=(lane>>4)*4+q
#pragma unroll
  for (int m = 0; m < 4; m++) {
#pragma unroll
    for (int j = 0; j < 4; j++) {
      int col = col0 + wc * 64 + (j >> 1) * 32 + (j & 1) * 16 + (lane & 15);
      float bv = BIAS ? bias[col] : 0.f;
#pragma unroll
      for (int q = 0; q < 4; q++) {
        int row = row0 + wr * 64 + m * 16 + (lane >> 4) * 4 + q;
        float v = fmaxf(acc[m][j][q] + bv, 0.f);
        if constexpr (OUTBF16) {
          ((__hip_bfloat16*)Cv + (size_t)blockIdx.z * strideC)
              [(size_t)row * N + col] = __float2bfloat16(v);
        } else {
          ((float*)Cv + (size_t)blockIdx.z * strideC)
              [(size_t)row * N + col] = v;
        }
      }
    }
  }
}

__global__ __launch_bounds__(256) void norm_kernel(
    const float* __restrict__ z, float* __restrict__ out) {
  int v = blockIdx.x, tid = threadIdx.x;
  const float* zr = z + (size_t)v * D_;
  float e0 = zr[tid], e1 = zr[tid + 256], e2 = zr[tid + 512];
  float q = e0 * e0 + e1 * e1 + e2 * e2;
  __shared__ float red[4];
  __shared__ float sc;
  float wq = wave_sum(q);
  int lane = tid & 63, w = tid >> 6;
  if (lane == 0) red[w] = wq;
  __syncthreads();
  if (tid == 0) {
    float S = red[0] + red[1] + red[2] + red[3];
    float norm = sqrtf(S);
    sc = (norm == 0.f) ? 1.f : (1.f / norm);
  }
  __syncthreads();
  float s = sc;
  float* orow = out + (size_t)v * D_;
  orow[tid]       = e0 * s;
  orow[tid + 256] = e1 * s;
  orow[tid + 512] = e2 * s;
}

extern "C" void kernel_launch(void* const* d_in, const int* in_sizes, int n_in,
                              void* d_out, int out_size, void* d_ws,
                              size_t ws_size, hipStream_t stream) {
  (void)in_sizes; (void)n_in; (void)out_size; (void)ws_size;
  const float* h      = (const float*)d_in[0];
  const float* W_text = (const float*)d_in[1];
  const float* c_text = (const float*)d_in[2];
  const float* W_user = (const float*)d_in[3];
  const float* c_user = (const float*)d_in[4];
  const float* W_dst  = (const float*)d_in[5];
  const float* c_dst  = (const float*)d_in[6];
  const float* gamma  = (const float*)d_in[7];
  const float* beta   = (const float*)d_in[8];
  const float* W_lin  = (const float*)d_in[9];
  const float* b_lin  = (const float*)d_in[10];
  const int* src      = (const int*)d_in[11];
  const int* dst      = (const int*)d_in[12];
  const int* etype    = (const int*)d_in[13];
  const int* hete     = (const int*)d_in[14];
  float* out          = (float*)d_out;

  char* ws = (char*)d_ws;
  __hip_bfloat16* xb   = (__hip_bfloat16*)(ws + OFF_XB);
  __hip_bfloat16* WcT  = (__hip_bfloat16*)(ws + OFF_WCT);
  __hip_bfloat16* WlT  = (__hip_bfloat16*)(ws + OFF_WLT);
  __hip_bfloat16* nb16 = (__hip_bfloat16*)(ws + OFF_NB16);
  __hip_bfloat16* H4   = (__hip_bfloat16*)(ws + OFF_H4);
  float* zbuf          = (float*)(ws + OFF_ZB);
  __hip_bfloat16* n1c  = (__hip_bfloat16*)(ws + OFF_N1C);
  int* target   = (int*)(ws + OFF_TG);
  int* payload  = (int*)(ws + OFF_PAY);
  int* cnt4     = (int*)(ws + OFF_CNT);
  int* base     = (int*)(ws + OFF_BASE);
  int* cursor   = (int*)(ws + OFF_CUR);
  int* blockcnt = (int*)(ws + OFF_BC);
  int* scanout  = (int*)(ws + OFF_SCAN);

  hipMemsetAsync(cnt4, 0, (size_t)N_ * 4 * 4, stream);
  hipMemsetAsync(cursor, 0, (size_t)N_ * 4, stream);

  combine_wt_kernel<<<dim3(DSQ_ / 256, 12), 256, 0, stream>>>(
      W_text, c_text, W_user, c_user, W_dst, c_dst, WcT);
  wlint_kernel<<<(D2_ * D_) / 256, 256, 0, stream>>>(W_lin, WlT);
  ln_kernel<<<N_, 256, 0, stream>>>(h, gamma, beta, xb);
  edge_a_kernel<<<E_ / 256, 256, 0, stream>>>(hete, dst, etype, blockcnt, cnt4);
  scan_kernel<<<1, 512, 0, stream>>>(blockcnt, scanout);
  edge_b_kernel<<<E_ / 256, 256, 0, stream>>>(hete, dst, scanout, target);
  base_scan_kernel<<<1, 1024, 0, stream>>>(cnt4, base);
  edge_sort_kernel<<<E_ / 256, 256, 0, stream>>>(target, src, etype, hete,
                                                 base, cursor, payload);

  const size_t HSTRIDE = (size_t)N_ * D_;
  const dim3 ggrid(D_ / 128, N_ / 256, 4);

  // dst family: 4 GEMMs batched (z) -> H4, then weighted combine into nb16
  gemm256_kernel<false, true><<<ggrid, 512, 0, stream>>>(
      xb, WcT + (size_t)8 * DSQ_, nullptr, H4, N_, D_, D_, DSQ_, HSTRIDE);
  combine_n2_kernel<<<(N_ * D_) / (256 * 8), 256, 0, stream>>>(H4, cnt4, nb16);

  // src families: 2 passes of 4 groups each
  gemm256_kernel<false, true><<<ggrid, 512, 0, stream>>>(
      xb, WcT, nullptr, H4, N_, D_, D_, DSQ_, HSTRIDE);
  gather_n1_kernel<true><<<N_ / 4, 256, 0, stream>>>(H4, base, payload, n1c,
                                                     nb16, 0);
  gemm256_kernel<false, true><<<ggrid, 512, 0, stream>>>(
      xb, WcT + (size_t)4 * DSQ_, nullptr, H4, N_, D_, D_, DSQ_, HSTRIDE);
  gather_n1_kernel<false><<<N_ / 4, 256, 0, stream>>>(H4, base, payload, n1c,
                                                      nb16, 4);

  // z = relu(nb16 @ W_lin + b_lin) -> zbuf (reuses H4), then norm
  gemm256_kernel<true, false><<<dim3(D_ / 128, N_ / 256, 1), 512, 0, stream>>>(
      nb16, WlT, b_lin, zbuf, N_, D_, D2_, 0, 0);
  norm_kernel<<<N_, 256, 0, stream>>>(zbuf, out);
}

// Round 9
// 494.675 us; speedup vs baseline: 1.1292x; 1.1292x over previous
//
#include <hip/hip_runtime.h>
#include <hip/hip_bf16.h>
#include <cstdint>

static constexpr int N_  = 16384;
static constexpr int E_  = 131072;
static constexpr int D_  = 768;
static constexpr int D2_ = 1536;
static constexpr int DSQ_ = D_ * D_;

// ---------------- workspace layout (bytes), total ~219.3 MB ----------------
static constexpr size_t OFF_XB   = 0;            // N*D bf16    = 25165824
static constexpr size_t OFF_WCT  = 25165824;     // 12*D*D bf16 = 14155776
static constexpr size_t OFF_WLT  = 39321600;     // D*2D bf16   = 2359296
static constexpr size_t OFF_NB16 = 41680896;     // N*2D bf16   = 50331648
static constexpr size_t OFF_H4   = 92012544;     // 4 * N*D bf16 = 100663296
static constexpr size_t OFF_ZB   = 92012544;     // N*D fp32 (reuses H4 after gathers)
static constexpr size_t OFF_N1C  = 192675840;    // N*D bf16 carry = 25165824
static constexpr size_t OFF_TG   = 217841664;    // E int32     = 524288
static constexpr size_t OFF_PAY  = 218365952;    // E int32     = 524288
static constexpr size_t OFF_CNT  = 218890240;    // N*4 int32   = 262144
static constexpr size_t OFF_BASE = 219152384;    // (N+1) int32, padded to 65552
static constexpr size_t OFF_CUR  = 219217936;    // N int32     = 65536
static constexpr size_t OFF_BC   = 219283472;    // 512 int32
static constexpr size_t OFF_SCAN = 219285520;    // 513 int32

typedef __attribute__((ext_vector_type(8))) short short8v;
typedef __attribute__((ext_vector_type(4))) float floatx4;

__device__ __forceinline__ void gld16(const void* g, void* l) {
  __builtin_amdgcn_global_load_lds(
      (const __attribute__((address_space(1))) unsigned int*)g,
      (__attribute__((address_space(3))) unsigned int*)l, 16, 0, 0);
}

__device__ __forceinline__ float b2f(short u) {
  union { unsigned int i; float f; } x;
  x.i = ((unsigned int)(unsigned short)u) << 16;
  return x.f;
}

__device__ __forceinline__ float wave_sum(float v) {
#pragma unroll
  for (int o = 32; o; o >>= 1) v += __shfl_down(v, o, 64);
  return v;
}

// WcT[ft][h][d] = sum_b coeff_f[t,b] * W_f[b][d][h]  (bf16, transposed)
__global__ __launch_bounds__(256) void combine_wt_kernel(
    const float* __restrict__ Wt, const float* __restrict__ ct,
    const float* __restrict__ Wu, const float* __restrict__ cu,
    const float* __restrict__ Wd, const float* __restrict__ cd,
    __hip_bfloat16* __restrict__ WcT) {
  int i  = blockIdx.x * 256 + threadIdx.x;   // < D*D, i = d*768 + h
  int ft = blockIdx.y;                        // 0..11
  int f = ft >> 2, t = ft & 3;
  const float* W = (f == 0) ? Wt : ((f == 1) ? Wu : Wd);
  const float* c = ((f == 0) ? ct : ((f == 1) ? cu : cd)) + t * 3;
  float v = c[0] * W[i] + c[1] * W[DSQ_ + i] + c[2] * W[2 * DSQ_ + i];
  int d = i / D_, h = i % D_;
  WcT[(size_t)ft * DSQ_ + (size_t)h * D_ + d] = __float2bfloat16(v);
}

// W_linT[h][k] = W_lin[k][h] (bf16)
__global__ __launch_bounds__(256) void wlint_kernel(
    const float* __restrict__ W, __hip_bfloat16* __restrict__ WT) {
  int i = blockIdx.x * 256 + threadIdx.x;    // < 2D*D, i = k*768 + h
  int k = i / D_, h = i % D_;
  WT[(size_t)h * D2_ + k] = __float2bfloat16(W[i]);
}

__global__ __launch_bounds__(256) void ln_kernel(
    const float* __restrict__ h, const float* __restrict__ gamma,
    const float* __restrict__ beta, __hip_bfloat16* __restrict__ x) {
  int v = blockIdx.x, tid = threadIdx.x;
  const float* hr = h + (size_t)v * D_;
  float e0 = hr[tid], e1 = hr[tid + 256], e2 = hr[tid + 512];
  float s = e0 + e1 + e2;
  float q = e0 * e0 + e1 * e1 + e2 * e2;
  __shared__ float red[8];
  __shared__ float mv[2];
  float ws_ = wave_sum(s), wq = wave_sum(q);
  int lane = tid & 63, w = tid >> 6;
  if (lane == 0) { red[w] = ws_; red[4 + w] = wq; }
  __syncthreads();
  if (tid == 0) {
    float S = red[0] + red[1] + red[2] + red[3];
    float Q = red[4] + red[5] + red[6] + red[7];
    float mu = S * (1.0f / D_);
    float var = Q * (1.0f / D_) - mu * mu;
    mv[0] = mu;
    mv[1] = rsqrtf(var + 1e-5f);
  }
  __syncthreads();
  float mu = mv[0], rstd = mv[1];
  __hip_bfloat16* xr = x + (size_t)v * D_;
  xr[tid]       = __float2bfloat16((e0 - mu) * rstd * gamma[tid]       + beta[tid]);
  xr[tid + 256] = __float2bfloat16((e1 - mu) * rstd * gamma[tid + 256] + beta[tid + 256]);
  xr[tid + 512] = __float2bfloat16((e2 - mu) * rstd * gamma[tid + 512] + beta[tid + 512]);
}

// per-block hete counts + (dst,etype) histogram
__global__ __launch_bounds__(256) void edge_a_kernel(
    const int* __restrict__ hete, const int* __restrict__ dst,
    const int* __restrict__ etype, int* __restrict__ blockcnt,
    int* __restrict__ cnt4) {
  int j = blockIdx.x * 256 + threadIdx.x;
  int flag = hete[j] > 0;
  unsigned long long m = __ballot(flag);
  __shared__ int wsum[4];
  int lane = threadIdx.x & 63, w = threadIdx.x >> 6;
  if (lane == 0) wsum[w] = __popcll(m);
  __syncthreads();
  if (threadIdx.x == 0)
    blockcnt[blockIdx.x] = wsum[0] + wsum[1] + wsum[2] + wsum[3];
  atomicAdd(&cnt4[dst[j] * 4 + etype[j]], 1);
}

// single-block scan over 512 block counts -> exclusive offsets + total K
__global__ __launch_bounds__(512) void scan_kernel(
    const int* __restrict__ blockcnt, int* __restrict__ scanout) {
  __shared__ int s[512];
  int t = threadIdx.x;
  int v = blockcnt[t];
  s[t] = v;
  __syncthreads();
  for (int o = 1; o < 512; o <<= 1) {
    int add = (t >= o) ? s[t - o] : 0;
    __syncthreads();
    s[t] += add;
    __syncthreads();
  }
  scanout[t] = s[t] - v;             // exclusive prefix
  if (t == 511) scanout[512] = s[511];  // total hete count K
}

// target[j] = dst[perm_inv[j]]
__global__ __launch_bounds__(256) void edge_b_kernel(
    const int* __restrict__ hete, const int* __restrict__ dst,
    const int* __restrict__ scanout, int* __restrict__ target) {
  int j = blockIdx.x * 256 + threadIdx.x;
  int flag = hete[j] > 0;
  unsigned long long m = __ballot(flag);
  __shared__ int wsum[4];
  int lane = threadIdx.x & 63, w = threadIdx.x >> 6;
  if (lane == 0) wsum[w] = __popcll(m);
  __syncthreads();
  int wpre = 0;
#pragma unroll
  for (int i = 0; i < 4; i++) wpre += (i < w) ? wsum[i] : 0;
  int lpre = __popcll(m & ((1ull << lane) - 1ull));
  int hcum = scanout[blockIdx.x] + wpre + lpre;  // # hete edges with idx < j
  int K = scanout[512];
  int e = flag ? hcum : (K + j - hcum);
  target[j] = dst[e];
}

// base[v] = exclusive prefix of deg[v] = sum_t cnt4[v,t]; base[N]=E
__global__ __launch_bounds__(1024) void base_scan_kernel(
    const int* __restrict__ cnt4, int* __restrict__ base) {
  __shared__ int s[1024];
  int t = threadIdx.x;
  int loc[16];
  int sum = 0;
#pragma unroll
  for (int i = 0; i < 16; i++) {
    int v = t * 16 + i;
    int d = cnt4[v * 4] + cnt4[v * 4 + 1] + cnt4[v * 4 + 2] + cnt4[v * 4 + 3];
    loc[i] = sum;
    sum += d;
  }
  s[t] = sum;
  __syncthreads();
  for (int o = 1; o < 1024; o <<= 1) {
    int add = (t >= o) ? s[t - o] : 0;
    __syncthreads();
    s[t] += add;
    __syncthreads();
  }
  int pre = t ? s[t - 1] : 0;
#pragma unroll
  for (int i = 0; i < 16; i++) base[t * 16 + i] = pre + loc[i];
  if (t == 1023) base[N_] = s[1023];
}

// payload[base[target[j]] + cursor++] = g<<14 | src[j]
__global__ __launch_bounds__(256) void edge_sort_kernel(
    const int* __restrict__ target, const int* __restrict__ src,
    const int* __restrict__ etype, const int* __restrict__ hete,
    const int* __restrict__ base, int* __restrict__ cursor,
    int* __restrict__ payload) {
  int j = blockIdx.x * 256 + threadIdx.x;
  int v = target[j];
  int p = base[v] + atomicAdd(&cursor[v], 1);
  int g = ((hete[j] > 0) ? 0 : 4) + etype[j];
  payload[p] = (g << 14) | src[j];
}

// one wave per node; groups [g0, g0+4). Lane owns elems [lane*8,+8) and
// [512+lane*4,+4) -> 16B + 8B vector loads per edge row (G13).
template <bool FIRST>
__global__ __launch_bounds__(256) void gather_n1_kernel(
    const __hip_bfloat16* __restrict__ H, const int* __restrict__ base,
    const int* __restrict__ payload, __hip_bfloat16* __restrict__ n1c,
    __hip_bfloat16* __restrict__ nb16, int g0) {
  int wv = threadIdx.x >> 6, lane = threadIdx.x & 63;
  int v = blockIdx.x * 4 + wv;
  int b0 = base[v], b1 = base[v + 1];
  float acc[12];
  if (FIRST) {
#pragma unroll
    for (int i = 0; i < 12; i++) acc[i] = 0.f;
  } else {
    short8v a8 = *(const short8v*)(n1c + (size_t)v * D_ + lane * 8);
    short4  b4 = *(const short4*)(n1c + (size_t)v * D_ + 512 + lane * 4);
#pragma unroll
    for (int i = 0; i < 8; i++) acc[i] = b2f(a8[i]);
    acc[8] = b2f(b4.x); acc[9] = b2f(b4.y);
    acc[10] = b2f(b4.z); acc[11] = b2f(b4.w);
  }
  for (int idx = b0; idx < b1; ++idx) {
    int pl = payload[idx];
    int g = (pl >> 14) - g0;
    if ((unsigned)g > 3u) continue;
    const __hip_bfloat16* row = H + ((size_t)g * N_ + (pl & 16383)) * D_;
    short8v a8 = *(const short8v*)(row + lane * 8);
    short4  b4 = *(const short4*)(row + 512 + lane * 4);
#pragma unroll
    for (int i = 0; i < 8; i++) acc[i] += b2f(a8[i]);
    acc[8] += b2f(b4.x); acc[9] += b2f(b4.y);
    acc[10] += b2f(b4.z); acc[11] += b2f(b4.w);
  }
  __hip_bfloat16 o[12];
#pragma unroll
  for (int i = 0; i < 12; i++) o[i] = __float2bfloat16(acc[i]);
  if (FIRST) {
    *(short8v*)(n1c + (size_t)v * D_ + lane * 8) = *(const short8v*)o;
    *(short4*)(n1c + (size_t)v * D_ + 512 + lane * 4) = *(const short4*)(o + 8);
  } else {
    *(short8v*)(nb16 + (size_t)v * D2_ + lane * 8) = *(const short8v*)o;
    *(short4*)(nb16 + (size_t)v * D2_ + 512 + lane * 4) = *(const short4*)(o + 8);
  }
}

// nb16[v][768+k] = sum_t cnt4[v,t] * H4[t][v][k]; thread per 8 elems
__global__ __launch_bounds__(256) void combine_n2_kernel(
    const __hip_bfloat16* __restrict__ H4, const int* __restrict__ cnt4,
    __hip_bfloat16* __restrict__ nb16) {
  size_t i = ((size_t)blockIdx.x * 256 + threadIdx.x) * 8;  // < N*D
  int v = (int)(i / D_);
  int k = (int)(i % D_);
  float acc[8] = {0.f, 0.f, 0.f, 0.f, 0.f, 0.f, 0.f, 0.f};
#pragma unroll
  for (int t = 0; t < 4; t++) {
    float c = (float)cnt4[v * 4 + t];
    if (c != 0.f) {
      short8v hv = *(const short8v*)(H4 + (size_t)t * N_ * D_ + i);
#pragma unroll
      for (int j = 0; j < 8; j++) acc[j] += c * b2f(hv[j]);
    }
  }
  __hip_bfloat16 o[8];
#pragma unroll
  for (int j = 0; j < 8; j++) o[j] = __float2bfloat16(acc[j]);
  *(short8v*)(nb16 + (size_t)v * D2_ + D_ + k) = *(const short8v*)o;
}

// ---- 8-phase 256x256 GEMM ----
// K-half unit = [256 rows][32 K] bf16 = 16 KB, stored as 128 lines x 128B:
// logical (r, p) (p = 16B k-slot 0..3) -> line u = r>>1, slot s = (r&1)*4+p,
// physical slot s ^ (u&7). Bijective (verified); reads are 2-way = free.
__device__ __forceinline__ int fragaddr(int r, int p) {
  int u = r >> 1;
  int s = ((r & 1) << 2) | p;
  return u * 128 + ((s ^ (u & 7)) << 4);
}

// stage one K-half unit (2 x gld16 per thread, 512 threads)
__device__ __forceinline__ void stage_kh(const __hip_bfloat16* X, int K,
                                         int rowbase, int kglob, char* unit,
                                         int tid) {
#pragma unroll
  for (int j = 0; j < 2; j++) {
    int q = j * 512 + tid;        // 16B slot 0..1023
    int u = q >> 3;               // 128B line
    int sp = q & 7;               // physical slot
    int s = sp ^ (u & 7);         // logical slot
    int r = (u << 1) | (s >> 2);
    int p = s & 3;
    gld16(X + (size_t)(rowbase + r) * K + kglob + p * 8, unit + q * 16);
  }
}

// C[z][M,N] = relu(A[M,K] @ BT[z][N,K]^T (+bias)). BM=BN=256, BK=64,
// 512 thr = 8 waves (2M x 4N), per-wave 128x64 out. LDS: 2 K-tile bufs x
// (A 32K + B 32K) = 128 KB. 8 phases / 2 K-tiles; phase (ks,ch): ch0 loads
// 8 A-frags + 2 B-frags, ch1 reuses A (2 reads). Staging cadence: phases 0-3
// stage tile 2i+1 -> buf1 (units A-k0, B-k0, A-k1, B-k1), phases 4-7 stage
// tile 2i+2 -> buf0. Derived waits: uniform vmcnt(4) at end of every odd
// phase (counted; each needed unit has exactly 4 younger loads), vmcnt(0)
// only at the last-iteration tail. Two barriers/phase (WAR: reads consumed
// by MFMAs before BAR_b -> post-BAR_b staging is safe).
template <bool BIAS, bool OUTBF16>
__global__ __launch_bounds__(512, 1) void gemm8p_kernel(
    const __hip_bfloat16* __restrict__ A, const __hip_bfloat16* __restrict__ BT0,
    const float* __restrict__ bias, void* __restrict__ Cv,
    int M, int N, int K, size_t strideB, size_t strideC) {
  __shared__ char lds[131072];
  const int tid = threadIdx.x, lane = tid & 63, wv = tid >> 6;
  const int wr = wv >> 2, wcn = wv & 3;
  // XCD swizzle over (bx, z, by): bx fastest, then z, then by -> each XCD
  // owns a contiguous by-range (A-panel chunk L2-resident, reused 4z x 3bx).
  int gx = gridDim.x, gz = gridDim.z;
  int nwg = gx * gridDim.y * gz;
  int id = (blockIdx.z * gridDim.y + blockIdx.y) * gx + blockIdx.x;
  int s = (id & 7) * (nwg >> 3) + (id >> 3);
  int bx = s % gx;
  int rem = s / gx;
  int z = rem % gz;
  int by = rem / gz;
  const __hip_bfloat16* BT = BT0 + (size_t)z * strideB;
  int row0 = by * 256, col0 = bx * 256;
  const int nt = K >> 6, ni = nt >> 1;

  floatx4 acc[8][4];
#pragma unroll
  for (int i = 0; i < 8; i++)
#pragma unroll
    for (int j = 0; j < 4; j++) acc[i][j] = floatx4{0.f, 0.f, 0.f, 0.f};

  // prologue: stage tile0 -> buf0 (order: A-k0, B-k0, A-k1, B-k1)
  stage_kh(A, K, row0, 0, lds, tid);
  stage_kh(BT, K, col0, 0, lds + 32768, tid);
  stage_kh(A, K, row0, 32, lds + 16384, tid);
  stage_kh(BT, K, col0, 32, lds + 49152, tid);
  asm volatile("s_waitcnt vmcnt(4)" ::: "memory");  // A-k0,B-k0 landed
  __builtin_amdgcn_s_barrier();
  asm volatile("" ::: "memory");

  for (int it = 0; it < ni; ++it) {
#pragma unroll
    for (int half = 0; half < 2; ++half) {
      char* rbuf = lds + (half << 16);
      char* sbuf = lds + ((half ^ 1) << 16);
      int stile = 2 * it + 1 + half;
      bool do_stage = stile < nt;
      int kg0 = stile * 64;
      short8v af[8];
#pragma unroll
      for (int ks = 0; ks < 2; ++ks) {
#pragma unroll
        for (int ch = 0; ch < 2; ++ch) {
          char* Au = rbuf + ks * 16384;
          char* Bu = rbuf + 32768 + ks * 16384;
          if (ch == 0) {
#pragma unroll
            for (int rf = 0; rf < 8; ++rf) {
              int r = wr * 128 + rf * 16 + (lane & 15);
              af[rf] = *(const short8v*)(Au + fragaddr(r, lane >> 4));
            }
          }
          short8v bfr[2];
#pragma unroll
          for (int nf = 0; nf < 2; ++nf) {
            int r = wcn * 64 + ch * 32 + nf * 16 + (lane & 15);
            bfr[nf] = *(const short8v*)(Bu + fragaddr(r, lane >> 4));
          }
          if (do_stage) {
            if (ch == 0)
              stage_kh(A, K, row0, kg0 + ks * 32, sbuf + ks * 16384, tid);
            else
              stage_kh(BT, K, col0, kg0 + ks * 32, sbuf + 32768 + ks * 16384,
                       tid);
          }
          asm volatile("" ::: "memory");
          __builtin_amdgcn_s_barrier();
          asm volatile("" ::: "memory");
          __builtin_amdgcn_s_setprio(1);
#pragma unroll
          for (int rf = 0; rf < 8; ++rf)
#pragma unroll
            for (int nf = 0; nf < 2; ++nf)
              acc[rf][ch * 2 + nf] = __builtin_amdgcn_mfma_f32_16x16x32_bf16(
                  af[rf], bfr[nf], acc[rf][ch * 2 + nf], 0, 0, 0);
          __builtin_amdgcn_s_setprio(0);
          if (ch == 1) {
            if (it == ni - 1 && half == 1) {
              if (ks == 0) asm volatile("s_waitcnt vmcnt(0)" ::: "memory");
            } else {
              asm volatile("s_waitcnt vmcnt(4)" ::: "memory");
            }
          }
          asm volatile("" ::: "memory");
          __builtin_amdgcn_s_barrier();
          asm volatile("" ::: "memory");
        }
      }
    }
  }
  // epilogue: C/D layout col=lane&15, row=(lane>>4)*4+q
#pragma unroll
  for (int rf = 0; rf < 8; ++rf) {
#pragma unroll
    for (int j = 0; j < 4; ++j) {
      int col = col0 + wcn * 64 + (j >> 1) * 32 + (j & 1) * 16 + (lane & 15);
      float bv = BIAS ? bias[col] : 0.f;
#pragma unroll
      for (int q = 0; q < 4; ++q) {
        int row = row0 + wr * 128 + rf * 16 + (lane >> 4) * 4 + q;
        float v = fmaxf(acc[rf][j][q] + bv, 0.f);
        if constexpr (OUTBF16) {
          ((__hip_bfloat16*)Cv + (size_t)z * strideC)[(size_t)row * N + col] =
              __float2bfloat16(v);
        } else {
          ((float*)Cv + (size_t)z * strideC)[(size_t)row * N + col] = v;
        }
      }
    }
  }
}

__global__ __launch_bounds__(256) void norm_kernel(
    const float* __restrict__ z, float* __restrict__ out) {
  int v = blockIdx.x, tid = threadIdx.x;
  const float* zr = z + (size_t)v * D_;
  float e0 = zr[tid], e1 = zr[tid + 256], e2 = zr[tid + 512];
  float q = e0 * e0 + e1 * e1 + e2 * e2;
  __shared__ float red[4];
  __shared__ float sc;
  float wq = wave_sum(q);
  int lane = tid & 63, w = tid >> 6;
  if (lane == 0) red[w] = wq;
  __syncthreads();
  if (tid == 0) {
    float S = red[0] + red[1] + red[2] + red[3];
    float norm = sqrtf(S);
    sc = (norm == 0.f) ? 1.f : (1.f / norm);
  }
  __syncthreads();
  float s = sc;
  float* orow = out + (size_t)v * D_;
  orow[tid]       = e0 * s;
  orow[tid + 256] = e1 * s;
  orow[tid + 512] = e2 * s;
}

extern "C" void kernel_launch(void* const* d_in, const int* in_sizes, int n_in,
                              void* d_out, int out_size, void* d_ws,
                              size_t ws_size, hipStream_t stream) {
  (void)in_sizes; (void)n_in; (void)out_size; (void)ws_size;
  const float* h      = (const float*)d_in[0];
  const float* W_text = (const float*)d_in[1];
  const float* c_text = (const float*)d_in[2];
  const float* W_user = (const float*)d_in[3];
  const float* c_user = (const float*)d_in[4];
  const float* W_dst  = (const float*)d_in[5];
  const float* c_dst  = (const float*)d_in[6];
  const float* gamma  = (const float*)d_in[7];
  const float* beta   = (const float*)d_in[8];
  const float* W_lin  = (const float*)d_in[9];
  const float* b_lin  = (const float*)d_in[10];
  const int* src      = (const int*)d_in[11];
  const int* dst      = (const int*)d_in[12];
  const int* etype    = (const int*)d_in[13];
  const int* hete     = (const int*)d_in[14];
  float* out          = (float*)d_out;

  char* ws = (char*)d_ws;
  __hip_bfloat16* xb   = (__hip_bfloat16*)(ws + OFF_XB);
  __hip_bfloat16* WcT  = (__hip_bfloat16*)(ws + OFF_WCT);
  __hip_bfloat16* WlT  = (__hip_bfloat16*)(ws + OFF_WLT);
  __hip_bfloat16* nb16 = (__hip_bfloat16*)(ws + OFF_NB16);
  __hip_bfloat16* H4   = (__hip_bfloat16*)(ws + OFF_H4);
  float* zbuf          = (float*)(ws + OFF_ZB);
  __hip_bfloat16* n1c  = (__hip_bfloat16*)(ws + OFF_N1C);
  int* target   = (int*)(ws + OFF_TG);
  int* payload  = (int*)(ws + OFF_PAY);
  int* cnt4     = (int*)(ws + OFF_CNT);
  int* base     = (int*)(ws + OFF_BASE);
  int* cursor   = (int*)(ws + OFF_CUR);
  int* blockcnt = (int*)(ws + OFF_BC);
  int* scanout  = (int*)(ws + OFF_SCAN);

  hipMemsetAsync(cnt4, 0, (size_t)N_ * 4 * 4, stream);
  hipMemsetAsync(cursor, 0, (size_t)N_ * 4, stream);

  combine_wt_kernel<<<dim3(DSQ_ / 256, 12), 256, 0, stream>>>(
      W_text, c_text, W_user, c_user, W_dst, c_dst, WcT);
  wlint_kernel<<<(D2_ * D_) / 256, 256, 0, stream>>>(W_lin, WlT);
  ln_kernel<<<N_, 256, 0, stream>>>(h, gamma, beta, xb);
  edge_a_kernel<<<E_ / 256, 256, 0, stream>>>(hete, dst, etype, blockcnt, cnt4);
  scan_kernel<<<1, 512, 0, stream>>>(blockcnt, scanout);
  edge_b_kernel<<<E_ / 256, 256, 0, stream>>>(hete, dst, scanout, target);
  base_scan_kernel<<<1, 1024, 0, stream>>>(cnt4, base);
  edge_sort_kernel<<<E_ / 256, 256, 0, stream>>>(target, src, etype, hete,
                                                 base, cursor, payload);

  const size_t HSTRIDE = (size_t)N_ * D_;
  const dim3 ggrid(D_ / 256, N_ / 256, 4);

  // dst family: 4 GEMMs batched (z) -> H4, then weighted combine into nb16
  gemm8p_kernel<false, true><<<ggrid, 512, 0, stream>>>(
      xb, WcT + (size_t)8 * DSQ_, nullptr, H4, N_, D_, D_, DSQ_, HSTRIDE);
  combine_n2_kernel<<<(N_ * D_) / (256 * 8), 256, 0, stream>>>(H4, cnt4, nb16);

  // src families: 2 passes of 4 groups each
  gemm8p_kernel<false, true><<<ggrid, 512, 0, stream>>>(
      xb, WcT, nullptr, H4, N_, D_, D_, DSQ_, HSTRIDE);
  gather_n1_kernel<true><<<N_ / 4, 256, 0, stream>>>(H4, base, payload, n1c,
                                                     nb16, 0);
  gemm8p_kernel<false, true><<<ggrid, 512, 0, stream>>>(
      xb, WcT + (size_t)4 * DSQ_, nullptr, H4, N_, D_, D_, DSQ_, HSTRIDE);
  gather_n1_kernel<false><<<N_ / 4, 256, 0, stream>>>(H4, base, payload, n1c,
                                                      nb16, 4);

  // z = relu(nb16 @ W_lin + b_lin) -> zbuf (reuses H4), then norm
  gemm8p_kernel<true, false><<<dim3(D_ / 256, N_ / 256, 1), 512, 0, stream>>>(
      nb16, WlT, b_lin, zbuf, N_, D_, D2_, 0, 0);
  norm_kernel<<<N_, 256, 0, stream>>>(zbuf, out);
}